// Round 1
// baseline (324.544 us; speedup 1.0000x reference)
//
#include <hip/hip_runtime.h>
#include <stdint.h>

typedef __bf16 bf16_t;
typedef __bf16 bf16x8 __attribute__((ext_vector_type(8)));
typedef __bf16 bf16x4 __attribute__((ext_vector_type(4)));
typedef float floatx4 __attribute__((ext_vector_type(4)));

// async global->LDS, 16B per lane. LDS dest is wave-uniform base; HW adds lane*16.
__device__ __forceinline__ void async_copy16(const bf16_t* g, bf16_t* l) {
  __builtin_amdgcn_global_load_lds(
      (const __attribute__((address_space(1))) void*)g,
      (__attribute__((address_space(3))) void*)l,
      16, 0, 0);
}

__global__ void cvt_f32_bf16(const float* __restrict__ s, bf16_t* __restrict__ d, long n) {
  long i = ((long)blockIdx.x * blockDim.x + threadIdx.x) * 4;
  if (i + 3 < n) {
    float4 f = *(const float4*)(s + i);
    bf16x4 o;
    o[0] = (bf16_t)f.x; o[1] = (bf16_t)f.y; o[2] = (bf16_t)f.z; o[3] = (bf16_t)f.w;
    *(bf16x4*)(d + i) = o;
  }
}

// C = alpha * (A @ B^T) (+ bias[n]).  A:[M,K] row-major (batch stride sA),
// B:[N,K] row-major (batch stride sB). All dims assumed multiples of tile sizes
// (M%128==0, N%128==0, K%32==0) -- true for every call here.
// OUT_MODE 0: bf16 row-major [M,N] (ldc=N)
// OUT_MODE 1: bf16 transposed [N,M] (ldc=M)  -- for kT/vT
// OUT_MODE 2: fp32 row-major [M,N]
template<int OUT_MODE, bool HAS_BIAS>
__global__ __launch_bounds__(256)
void gemm_nt(const bf16_t* __restrict__ A, const bf16_t* __restrict__ B,
             void* __restrict__ C, const float* __restrict__ bias,
             int K, long sA, long sB, long sC, int ldc, float alpha) {
  __shared__ bf16_t As[128 * 32];
  __shared__ bf16_t Bs[128 * 32];
  const int tid  = threadIdx.x;
  const int lane = tid & 63;
  const int w    = tid >> 6;        // wave 0..3
  const int wr   = w >> 1, wc = w & 1;
  const int quad = lane >> 4, lm = lane & 15;
  const int z  = blockIdx.z;
  const int m0 = blockIdx.y * 128;
  const int n0 = blockIdx.x * 128;

  const bf16_t* Ab = A + (long)z * sA;
  const bf16_t* Bb = B + (long)z * sB;

  // staging: each 16-row x 32-col chunk = 1024B = one wave-wide load_lds x16.
  // wave w handles chunks {w, w+4} of A and of B.
  const int ar = lane >> 2;          // row within chunk
  const int ak = (lane & 3) * 8;     // k element offset
  const bf16_t* ag0 = Ab + (long)(m0 + w * 16 + ar) * K + ak;
  const bf16_t* ag1 = ag0 + (long)64 * K;
  const bf16_t* bg0 = Bb + (long)(n0 + w * 16 + ar) * K + ak;
  const bf16_t* bg1 = bg0 + (long)64 * K;
  bf16_t* la0 = &As[w * 512];
  bf16_t* la1 = la0 + 2048;
  bf16_t* lb0 = &Bs[w * 512];
  bf16_t* lb1 = lb0 + 2048;

  floatx4 acc[4][4];
#pragma unroll
  for (int r = 0; r < 4; r++)
#pragma unroll
    for (int c = 0; c < 4; c++)
      acc[r][c] = (floatx4){0.f, 0.f, 0.f, 0.f};

  for (int k0 = 0; k0 < K; k0 += 32) {
    async_copy16(ag0 + k0, la0);
    async_copy16(ag1 + k0, la1);
    async_copy16(bg0 + k0, lb0);
    async_copy16(bg1 + k0, lb1);
    __syncthreads();   // drains vmcnt(0): LDS tiles ready

    bf16x8 afr[4], bfr[4];
#pragma unroll
    for (int r = 0; r < 4; r++)
      afr[r] = *(const bf16x8*)&As[(wr * 64 + r * 16 + lm) * 32 + quad * 8];
#pragma unroll
    for (int c = 0; c < 4; c++)
      bfr[c] = *(const bf16x8*)&Bs[(wc * 64 + c * 16 + lm) * 32 + quad * 8];
#pragma unroll
    for (int r = 0; r < 4; r++)
#pragma unroll
      for (int c = 0; c < 4; c++)
        acc[r][c] = __builtin_amdgcn_mfma_f32_16x16x32_bf16(afr[r], bfr[c], acc[r][c], 0, 0, 0);
    __syncthreads();   // protect LDS before next stage overwrites
  }

  const int rowBase = m0 + wr * 64;
  const int colBase = n0 + wc * 64;

  if (OUT_MODE == 2) {
    float* Cf = (float*)C + (long)z * sC;
#pragma unroll
    for (int r = 0; r < 4; r++) {
      const int row = rowBase + r * 16 + quad * 4;
#pragma unroll
      for (int c = 0; c < 4; c++) {
        const int col = colBase + c * 16 + lm;
        const float bv = HAS_BIAS ? bias[col] : 0.f;
#pragma unroll
        for (int i = 0; i < 4; i++)
          Cf[(long)(row + i) * ldc + col] = acc[r][c][i] * alpha + bv;
      }
    }
  } else if (OUT_MODE == 0) {
    bf16_t* Cb = (bf16_t*)C + (long)z * sC;
#pragma unroll
    for (int r = 0; r < 4; r++) {
      const int row = rowBase + r * 16 + quad * 4;
#pragma unroll
      for (int c = 0; c < 4; c++) {
        const int col = colBase + c * 16 + lm;
        const float bv = HAS_BIAS ? bias[col] : 0.f;
#pragma unroll
        for (int i = 0; i < 4; i++)
          Cb[(long)(row + i) * ldc + col] = (bf16_t)(acc[r][c][i] * alpha + bv);
      }
    }
  } else {  // OUT_MODE == 1: transposed bf16, C[n*ldc + m]; 4 consecutive rows/lane -> 8B store
    bf16_t* Cb = (bf16_t*)C + (long)z * sC;
#pragma unroll
    for (int r = 0; r < 4; r++) {
      const int row = rowBase + r * 16 + quad * 4;
#pragma unroll
      for (int c = 0; c < 4; c++) {
        const int col = colBase + c * 16 + lm;
        const float bv = HAS_BIAS ? bias[col] : 0.f;
        bf16x4 pk;
#pragma unroll
        for (int i = 0; i < 4; i++)
          pk[i] = (bf16_t)(acc[r][c][i] * alpha + bv);
        *(bf16x4*)(Cb + (long)col * ldc + row) = pk;
      }
    }
  }
}

extern "C" void kernel_launch(void* const* d_in, const int* in_sizes, int n_in,
                              void* d_out, int out_size, void* d_ws, size_t ws_size,
                              hipStream_t stream) {
  const float* x  = (const float*)d_in[0];
  const float* Wq = (const float*)d_in[1];
  const float* bq = (const float*)d_in[2];
  const float* Wk = (const float*)d_in[3];
  const float* bk = (const float*)d_in[4];
  const float* Wv = (const float*)d_in[5];
  const float* bv = (const float*)d_in[6];
  const float* Wo = (const float*)d_in[7];
  const float* bo = (const float*)d_in[8];
  float* out = (float*)d_out;

  // B=4, S=2048, E=1024
  const long NX = 8192L * 1024;   // x / q / kT / vT / outb elements
  const long NW = 1024L * 1024;   // weight elements
  const long NM = 4L * 1024 * 1024; // Mt elements (B x E x E)

  bf16_t* ws   = (bf16_t*)d_ws;     // ~96 MiB of bf16 scratch
  bf16_t* xb   = ws;
  bf16_t* Wqb  = xb + NX;
  bf16_t* Wkb  = Wqb + NW;
  bf16_t* Wvb  = Wkb + NW;
  bf16_t* Wob  = Wvb + NW;
  bf16_t* qb   = Wob + NW;
  bf16_t* kT   = qb + NX;           // [B][E][S]
  bf16_t* vT   = kT + NX;           // [B][E][S]
  bf16_t* Mt   = vT + NX;           // [B][E][E], Mt[e,f] = scale*sum_t v[t,e]k[t,f]
  bf16_t* outb = Mt + NM;           // [B][S][E]

  cvt_f32_bf16<<<NX / 1024, 256, 0, stream>>>(x, xb, NX);
  cvt_f32_bf16<<<NW / 1024, 256, 0, stream>>>(Wq, Wqb, NW);
  cvt_f32_bf16<<<NW / 1024, 256, 0, stream>>>(Wk, Wkb, NW);
  cvt_f32_bf16<<<NW / 1024, 256, 0, stream>>>(Wv, Wvb, NW);
  cvt_f32_bf16<<<NW / 1024, 256, 0, stream>>>(Wo, Wob, NW);

  dim3 blk(256);
  dim3 gproj(1024 / 128, 2048 / 128, 4);   // N/128, M/128, batch
  dim3 gmt(1024 / 128, 1024 / 128, 4);

  // q = x@Wq^T + bq  -> bf16 [B*S, E]
  gemm_nt<0, true><<<gproj, blk, 0, stream>>>(xb, Wqb, qb, bq,
      1024, 2048L * 1024, 0L, 2048L * 1024, 1024, 1.0f);
  // kT = (x@Wk^T + bk)^T  -> bf16 [B][E][S]
  gemm_nt<1, true><<<gproj, blk, 0, stream>>>(xb, Wkb, kT, bk,
      1024, 2048L * 1024, 0L, 1024L * 2048, 2048, 1.0f);
  // vT = (x@Wv^T + bv)^T  -> bf16 [B][E][S]
  gemm_nt<1, true><<<gproj, blk, 0, stream>>>(xb, Wvb, vT, bv,
      1024, 2048L * 1024, 0L, 1024L * 2048, 2048, 1.0f);
  // Mt[e,f] = scale * sum_t vT[e,t]*kT[f,t]   (NT, K=2048)
  gemm_nt<0, false><<<gmt, blk, 0, stream>>>(vT, kT, Mt, nullptr,
      2048, 1024L * 2048, 1024L * 2048, 1024L * 1024, 1024, 0.125f);
  // out[s,e] = sum_f q[s,f]*Mt[e,f]   (NT, K=1024)
  gemm_nt<0, false><<<gproj, blk, 0, stream>>>(qb, Mt, outb, nullptr,
      1024, 2048L * 1024, 1024L * 1024, 2048L * 1024, 1024, 1.0f);
  // final = out@Wo^T + bo  -> fp32 d_out
  gemm_nt<2, true><<<gproj, blk, 0, stream>>>(outb, Wob, out, bo,
      1024, 2048L * 1024, 0L, 2048L * 1024, 1024, 1.0f);
}

// Round 2
// 322.041 us; speedup vs baseline: 1.0078x; 1.0078x over previous
//
#include <hip/hip_runtime.h>
#include <stdint.h>

typedef __bf16 bf16_t;
typedef __bf16 bf16x8 __attribute__((ext_vector_type(8)));
typedef __bf16 bf16x4 __attribute__((ext_vector_type(4)));
typedef float floatx4 __attribute__((ext_vector_type(4)));

__device__ __forceinline__ void async_copy16(const bf16_t* g, bf16_t* l) {
  __builtin_amdgcn_global_load_lds(
      (const __attribute__((address_space(1))) void*)g,
      (__attribute__((address_space(3))) void*)l, 16, 0, 0);
}

// ---------- converts ----------
struct CvtSeg { const float* s; bf16_t* d; long n; };
struct CvtArgs { CvtSeg seg[5]; };

__global__ void cvt_multi(CvtArgs a) {
  CvtSeg sg = a.seg[blockIdx.y];
  long i = ((long)blockIdx.x * blockDim.x + threadIdx.x) * 4;
  if (i < sg.n) {
    float4 f = *(const float4*)(sg.s + i);
    bf16x4 o;
    o[0] = (bf16_t)f.x; o[1] = (bf16_t)f.y; o[2] = (bf16_t)f.z; o[3] = (bf16_t)f.w;
    *(bf16x4*)(sg.d + i) = o;
  }
}

__global__ void cvt_f32_bf16(const float* __restrict__ s, bf16_t* __restrict__ d, long n) {
  long i = ((long)blockIdx.x * blockDim.x + threadIdx.x) * 4;
  if (i < n) {
    float4 f = *(const float4*)(s + i);
    bf16x4 o;
    o[0] = (bf16_t)f.x; o[1] = (bf16_t)f.y; o[2] = (bf16_t)f.z; o[3] = (bf16_t)f.w;
    *(bf16x4*)(d + i) = o;
  }
}

__global__ void zero_f32(float* __restrict__ p, long n) {
  long i = ((long)blockIdx.x * blockDim.x + threadIdx.x) * 4;
  if (i < n) *(float4*)(p + i) = (float4){0.f, 0.f, 0.f, 0.f};
}

// ---------- GEMM core: 128x128 tile, BK=32, dbuf LDS, xor-swizzled staging ----------
// C = A @ B^T ; A:[*,lda] rows m0..m0+127, B:[*,ldb] rows n0..n0+127.
// As/Bs: 2 x 4096 bf16 (8KB each buffer). nk = number of 32-wide K steps.
__device__ __forceinline__ void gemm_core(
    const bf16_t* __restrict__ Ab, const bf16_t* __restrict__ Bb,
    int lda, int ldb, int nk, bf16_t* As, bf16_t* Bs,
    int m0, int n0, floatx4 (&acc)[4][4]) {
  const int tid  = threadIdx.x;
  const int lane = tid & 63;
  const int w    = tid >> 6;
  const int wr   = w >> 1, wc = w & 1;
  const int quad = lane >> 4, lm = lane & 15;
  // staging: lane -> (row ar, LDS k-slot lane&3); global k-chunk is slot^swz(ar)
  const int ar = lane >> 2;
  const int ak = (((lane & 3) ^ ((ar >> 1) & 3))) * 8;
  const bf16_t* ag0 = Ab + (long)(m0 + w * 16 + ar) * lda + ak;
  const bf16_t* ag1 = ag0 + (long)64 * lda;
  const bf16_t* bg0 = Bb + (long)(n0 + w * 16 + ar) * ldb + ak;
  const bf16_t* bg1 = bg0 + (long)64 * ldb;
  const int swz = (lm >> 1) & 3;   // reader-side slot swizzle

  // prologue: stage tile 0 into buf 0
  {
    bf16_t* la = As + w * 512;
    bf16_t* lb = Bs + w * 512;
    async_copy16(ag0, la);
    async_copy16(ag1, la + 2048);
    async_copy16(bg0, lb);
    async_copy16(bg1, lb + 2048);
  }
  for (int i = 0; i < nk; i++) {
    __syncthreads();                 // drains vmcnt(0): tile i resident
    if (i + 1 < nk) {                // prefetch tile i+1 into other buffer
      const int buf = (i + 1) & 1;
      const int k0  = (i + 1) * 32;
      bf16_t* la = As + buf * 4096 + w * 512;
      bf16_t* lb = Bs + buf * 4096 + w * 512;
      async_copy16(ag0 + k0, la);
      async_copy16(ag1 + k0, la + 2048);
      async_copy16(bg0 + k0, lb);
      async_copy16(bg1 + k0, lb + 2048);
    }
    const bf16_t* Ar = As + (i & 1) * 4096;
    const bf16_t* Br = Bs + (i & 1) * 4096;
    bf16x8 afr[4], bfr[4];
#pragma unroll
    for (int r = 0; r < 4; r++)
      afr[r] = *(const bf16x8*)&Ar[(wr * 64 + r * 16 + lm) * 32 + (quad ^ swz) * 8];
#pragma unroll
    for (int c = 0; c < 4; c++)
      bfr[c] = *(const bf16x8*)&Br[(wc * 64 + c * 16 + lm) * 32 + (quad ^ swz) * 8];
#pragma unroll
    for (int r = 0; r < 4; r++)
#pragma unroll
      for (int c = 0; c < 4; c++)
        acc[r][c] = __builtin_amdgcn_mfma_f32_16x16x32_bf16(afr[r], bfr[c], acc[r][c], 0, 0, 0);
  }
}

// ---------- fused q / kT / vT projections ----------
// grid: (E/128, S/128, 12); z = proj*4 + batch
__global__ __launch_bounds__(256) void qkv_fused(
    const bf16_t* __restrict__ xb,
    const bf16_t* __restrict__ Wq, const bf16_t* __restrict__ Wk, const bf16_t* __restrict__ Wv,
    const float* __restrict__ bq, const float* __restrict__ bk, const float* __restrict__ bv,
    bf16_t* __restrict__ qout, bf16_t* __restrict__ kT, bf16_t* __restrict__ vT) {
  __shared__ bf16_t As[8192], Bs[8192];
  const int z = blockIdx.z, batch = z & 3, proj = z >> 2;
  const bf16_t* W    = (proj == 0) ? Wq : (proj == 1) ? Wk : Wv;
  const float*  bias = (proj == 0) ? bq : (proj == 1) ? bk : bv;
  const int m0 = blockIdx.y * 128, n0 = blockIdx.x * 128;

  floatx4 acc[4][4];
#pragma unroll
  for (int r = 0; r < 4; r++)
#pragma unroll
    for (int c = 0; c < 4; c++) acc[r][c] = (floatx4){0.f, 0.f, 0.f, 0.f};

  gemm_core(xb + (long)batch * (2048L * 1024), W, 1024, 1024, 32, As, Bs, m0, n0, acc);

  const int lane = threadIdx.x & 63, w = threadIdx.x >> 6;
  const int wr = w >> 1, wc = w & 1, quad = lane >> 4, lm = lane & 15;
  const int rowBase = m0 + wr * 64, colBase = n0 + wc * 64;

  if (proj == 0) {  // q: row-major bf16 [S,E]
    bf16_t* C = qout + (long)batch * (2048L * 1024);
#pragma unroll
    for (int r = 0; r < 4; r++) {
      const int row = rowBase + r * 16 + quad * 4;
#pragma unroll
      for (int c = 0; c < 4; c++) {
        const int col = colBase + c * 16 + lm;
        const float bv_ = bias[col];
#pragma unroll
        for (int i = 0; i < 4; i++)
          C[(long)(row + i) * 1024 + col] = (bf16_t)(acc[r][c][i] + bv_);
      }
    }
  } else {          // kT / vT: transposed bf16 [E,S]
    bf16_t* C = ((proj == 1) ? kT : vT) + (long)batch * (1024L * 2048);
#pragma unroll
    for (int r = 0; r < 4; r++) {
      const int row = rowBase + r * 16 + quad * 4;
#pragma unroll
      for (int c = 0; c < 4; c++) {
        const int col = colBase + c * 16 + lm;
        const float bv_ = bias[col];
        bf16x4 pk;
#pragma unroll
        for (int i = 0; i < 4; i++) pk[i] = (bf16_t)(acc[r][c][i] + bv_);
        *(bf16x4*)(C + (long)col * 2048 + row) = pk;
      }
    }
  }
}

// ---------- generic NT GEMM ----------
// OUT_MODE 0: bf16 row-major; 2: fp32 row-major (+bias); 3: fp32 atomicAdd (split-K)
template<int OUT_MODE, bool HAS_BIAS, int KSPLIT>
__global__ __launch_bounds__(256) void gemm_nt(
    const bf16_t* __restrict__ A, const bf16_t* __restrict__ B,
    void* __restrict__ C, const float* __restrict__ bias,
    int lda, int ldb, int nk, long sA, long sB, long sC, int ldc, float alpha) {
  __shared__ bf16_t As[8192], Bs[8192];
  const int z     = blockIdx.z;
  const int batch = (KSPLIT > 1) ? (z / KSPLIT) : z;
  const int kch   = (KSPLIT > 1) ? (z % KSPLIT) : 0;
  const bf16_t* Ab = A + (long)batch * sA + (long)kch * (nk * 32);
  const bf16_t* Bb = B + (long)batch * sB + (long)kch * (nk * 32);
  const int m0 = blockIdx.y * 128, n0 = blockIdx.x * 128;

  floatx4 acc[4][4];
#pragma unroll
  for (int r = 0; r < 4; r++)
#pragma unroll
    for (int c = 0; c < 4; c++) acc[r][c] = (floatx4){0.f, 0.f, 0.f, 0.f};

  gemm_core(Ab, Bb, lda, ldb, nk, As, Bs, m0, n0, acc);

  const int lane = threadIdx.x & 63, w = threadIdx.x >> 6;
  const int wr = w >> 1, wc = w & 1, quad = lane >> 4, lm = lane & 15;
  const int rowBase = m0 + wr * 64, colBase = n0 + wc * 64;

  if (OUT_MODE == 0) {
    bf16_t* Cb = (bf16_t*)C + (long)batch * sC;
#pragma unroll
    for (int r = 0; r < 4; r++) {
      const int row = rowBase + r * 16 + quad * 4;
#pragma unroll
      for (int c = 0; c < 4; c++) {
        const int col = colBase + c * 16 + lm;
        const float bv_ = HAS_BIAS ? bias[col] : 0.f;
#pragma unroll
        for (int i = 0; i < 4; i++)
          Cb[(long)(row + i) * ldc + col] = (bf16_t)(acc[r][c][i] * alpha + bv_);
      }
    }
  } else if (OUT_MODE == 2) {
    float* Cf = (float*)C + (long)batch * sC;
#pragma unroll
    for (int r = 0; r < 4; r++) {
      const int row = rowBase + r * 16 + quad * 4;
#pragma unroll
      for (int c = 0; c < 4; c++) {
        const int col = colBase + c * 16 + lm;
        const float bv_ = HAS_BIAS ? bias[col] : 0.f;
#pragma unroll
        for (int i = 0; i < 4; i++)
          Cf[(long)(row + i) * ldc + col] = acc[r][c][i] * alpha + bv_;
      }
    }
  } else {  // OUT_MODE == 3: fp32 atomic accumulate
    float* Cf = (float*)C + (long)batch * sC;
#pragma unroll
    for (int r = 0; r < 4; r++) {
      const int row = rowBase + r * 16 + quad * 4;
#pragma unroll
      for (int c = 0; c < 4; c++) {
        const int col = colBase + c * 16 + lm;
#pragma unroll
        for (int i = 0; i < 4; i++)
          atomicAdd(&Cf[(long)(row + i) * ldc + col], acc[r][c][i] * alpha);
      }
    }
  }
}

extern "C" void kernel_launch(void* const* d_in, const int* in_sizes, int n_in,
                              void* d_out, int out_size, void* d_ws, size_t ws_size,
                              hipStream_t stream) {
  const float* x  = (const float*)d_in[0];
  const float* Wq = (const float*)d_in[1];
  const float* bq = (const float*)d_in[2];
  const float* Wk = (const float*)d_in[3];
  const float* bk = (const float*)d_in[4];
  const float* Wv = (const float*)d_in[5];
  const float* bv = (const float*)d_in[6];
  const float* Wo = (const float*)d_in[7];
  const float* bo = (const float*)d_in[8];
  float* out = (float*)d_out;

  // B=4, S=2048, E=1024
  const long NX = 8192L * 1024;      // x/q/kT/vT element count
  const long NW = 1024L * 1024;      // weight element count
  const long NM = 4L * 1024 * 1024;  // per-batch ExE accumulators

  bf16_t* ws  = (bf16_t*)d_ws;
  bf16_t* xb  = ws;
  bf16_t* Wqb = xb + NX;
  bf16_t* Wkb = Wqb + NW;
  bf16_t* Wvb = Wkb + NW;
  bf16_t* Wob = Wvb + NW;
  bf16_t* qb  = Wob + NW;
  bf16_t* kT  = qb + NX;             // [B][E][S]
  bf16_t* vT  = kT + NX;             // [B][E][S]
  float*  Mtf = (float*)(vT + NX);   // [B][E][E] fp32 split-K accumulator
  bf16_t* MtTb = vT;                 // reuse: vT dead after MtT GEMM
  bf16_t* Gb   = kT;                 // reuse: kT dead after MtT GEMM

  // converts (one dispatch)
  CvtArgs ca;
  ca.seg[0] = {x,  xb,  NX};
  ca.seg[1] = {Wq, Wqb, NW};
  ca.seg[2] = {Wk, Wkb, NW};
  ca.seg[3] = {Wv, Wvb, NW};
  ca.seg[4] = {Wo, Wob, NW};
  cvt_multi<<<dim3(NX / 1024, 5), 256, 0, stream>>>(ca);

  zero_f32<<<NM / 1024, 256, 0, stream>>>(Mtf, NM);

  // q / kT / vT fused: 1536 blocks
  qkv_fused<<<dim3(8, 16, 12), 256, 0, stream>>>(xb, Wqb, Wkb, Wvb, bq, bk, bv, qb, kT, vT);

  // MtT[f,e] = scale * sum_t kT[f,t]*vT[e,t]  -- split-K x4 -> fp32 atomics
  gemm_nt<3, false, 4><<<dim3(8, 8, 16), 256, 0, stream>>>(
      kT, vT, Mtf, nullptr, 2048, 2048, 16,
      1024L * 2048, 1024L * 2048, 1024L * 1024, 1024, 0.125f);

  cvt_f32_bf16<<<NM / 1024, 256, 0, stream>>>(Mtf, MtTb, NM);

  // G[i,f] = sum_e Wo[i,e] * MtT[f,e]   (A=Wo stride 0, B=MtT)
  gemm_nt<0, false, 1><<<dim3(8, 8, 4), 256, 0, stream>>>(
      Wob, MtTb, Gb, nullptr, 1024, 1024, 32,
      0L, 1024L * 1024, 1024L * 1024, 1024, 1.0f);

  // final[s,i] = sum_f q[s,f] * G[i,f] + bo[i]  -> fp32 d_out
  gemm_nt<2, true, 1><<<dim3(8, 16, 4), 256, 0, stream>>>(
      qb, Gb, out, bo, 1024, 1024, 32,
      2048L * 1024, 1024L * 1024, 2048L * 1024, 1024, 1.0f);
}

// Round 5
// 243.739 us; speedup vs baseline: 1.3315x; 1.3213x over previous
//
#include <hip/hip_runtime.h>
#include <stdint.h>

typedef __bf16 bf16_t;
typedef __bf16 bf16x8 __attribute__((ext_vector_type(8)));
typedef __bf16 bf16x4 __attribute__((ext_vector_type(4)));
typedef float floatx4 __attribute__((ext_vector_type(4)));

__device__ __forceinline__ void async_copy16(const bf16_t* g, bf16_t* l) {
  __builtin_amdgcn_global_load_lds(
      (const __attribute__((address_space(1))) void*)g,
      (__attribute__((address_space(3))) void*)l, 16, 0, 0);
}

// ---------- converts / reduce ----------
struct CvtSeg { const float* s; bf16_t* d; long n; };
struct CvtArgs { CvtSeg seg[5]; };

__global__ void cvt_multi(CvtArgs a) {
  CvtSeg sg = a.seg[blockIdx.y];
  long i = ((long)blockIdx.x * blockDim.x + threadIdx.x) * 4;
  if (i < sg.n) {
    float4 f = *(const float4*)(sg.s + i);
    bf16x4 o;
    o[0] = (bf16_t)f.x; o[1] = (bf16_t)f.y; o[2] = (bf16_t)f.z; o[3] = (bf16_t)f.w;
    *(bf16x4*)(sg.d + i) = o;
  }
}

__global__ void reduce2_cvt(const float* __restrict__ a, const float* __restrict__ b,
                            bf16_t* __restrict__ d, long n) {
  long i = ((long)blockIdx.x * blockDim.x + threadIdx.x) * 4;
  if (i < n) {
    float4 x = *(const float4*)(a + i);
    float4 y = *(const float4*)(b + i);
    bf16x4 o;
    o[0] = (bf16_t)(x.x + y.x); o[1] = (bf16_t)(x.y + y.y);
    o[2] = (bf16_t)(x.z + y.z); o[3] = (bf16_t)(x.w + y.w);
    *(bf16x4*)(d + i) = o;
  }
}

// ---------- GEMM core: 128x128 tile, BK=32, dbuf LDS, xor-swizzled staging ----------
__device__ __forceinline__ void gemm_core(
    const bf16_t* __restrict__ Ab, const bf16_t* __restrict__ Bb,
    int lda, int ldb, int nk, bf16_t* As, bf16_t* Bs,
    int m0, int n0, floatx4 (&acc)[4][4]) {
  const int tid  = threadIdx.x;
  const int lane = tid & 63;
  const int w    = tid >> 6;
  const int wr   = w >> 1, wc = w & 1;
  const int quad = lane >> 4, lm = lane & 15;
  const int ar = lane >> 2;
  const int ak = (((lane & 3) ^ ((ar >> 1) & 3))) * 8;
  const bf16_t* ag0 = Ab + (long)(m0 + w * 16 + ar) * lda + ak;
  const bf16_t* ag1 = ag0 + (long)64 * lda;
  const bf16_t* bg0 = Bb + (long)(n0 + w * 16 + ar) * ldb + ak;
  const bf16_t* bg1 = bg0 + (long)64 * ldb;
  const int swz = (lm >> 1) & 3;

  {
    bf16_t* la = As + w * 512;
    bf16_t* lb = Bs + w * 512;
    async_copy16(ag0, la);
    async_copy16(ag1, la + 2048);
    async_copy16(bg0, lb);
    async_copy16(bg1, lb + 2048);
  }
  for (int i = 0; i < nk; i++) {
    __syncthreads();
    if (i + 1 < nk) {
      const int buf = (i + 1) & 1;
      const int k0  = (i + 1) * 32;
      bf16_t* la = As + buf * 4096 + w * 512;
      bf16_t* lb = Bs + buf * 4096 + w * 512;
      async_copy16(ag0 + k0, la);
      async_copy16(ag1 + k0, la + 2048);
      async_copy16(bg0 + k0, lb);
      async_copy16(bg1 + k0, lb + 2048);
    }
    const bf16_t* Ar = As + (i & 1) * 4096;
    const bf16_t* Br = Bs + (i & 1) * 4096;
    bf16x8 afr[4], bfr[4];
#pragma unroll
    for (int r = 0; r < 4; r++)
      afr[r] = *(const bf16x8*)&Ar[(wr * 64 + r * 16 + lm) * 32 + (quad ^ swz) * 8];
#pragma unroll
    for (int c = 0; c < 4; c++)
      bfr[c] = *(const bf16x8*)&Br[(wc * 64 + c * 16 + lm) * 32 + (quad ^ swz) * 8];
#pragma unroll
    for (int r = 0; r < 4; r++)
#pragma unroll
      for (int c = 0; c < 4; c++)
        acc[r][c] = __builtin_amdgcn_mfma_f32_16x16x32_bf16(afr[r], bfr[c], acc[r][c], 0, 0, 0);
  }
}

// ---------- fused q / kT / vT: one block computes all 3 projections for one tile ----------
__global__ __launch_bounds__(256, 2) void qkv3(
    const bf16_t* __restrict__ xb,
    const bf16_t* __restrict__ Wq, const bf16_t* __restrict__ Wk, const bf16_t* __restrict__ Wv,
    const float* __restrict__ bq, const float* __restrict__ bk, const float* __restrict__ bv,
    bf16_t* __restrict__ qout, bf16_t* __restrict__ kT, bf16_t* __restrict__ vT) {
  __shared__ bf16_t As[2 * 4096];
  __shared__ bf16_t Bsh[3][2 * 4096];
  const int L = blockIdx.x + (blockIdx.y << 3) + (blockIdx.z << 7);
  const int V = (L & 7) * 64 + (L >> 3);
  const int batch = V >> 7;
  const int rr_   = V & 127;
  const int n0 = (rr_ & 7) * 128;
  const int m0 = (rr_ >> 3) * 128;

  const int tid = threadIdx.x, lane = tid & 63, w = tid >> 6;
  const int wr = w >> 1, wc = w & 1, quad = lane >> 4, lm = lane & 15;
  const int ar = lane >> 2;
  const int ak = (((lane & 3) ^ ((ar >> 1) & 3))) * 8;
  const int swz = (lm >> 1) & 3;

  const bf16_t* ag0 = xb + (long)batch * (2048L * 1024) + (long)(m0 + w * 16 + ar) * 1024 + ak;
  const bf16_t* ag1 = ag0 + 64L * 1024;
  const bf16_t* Wp[3] = {Wq, Wk, Wv};
  const bf16_t* bg0[3];
  const bf16_t* bg1[3];
#pragma unroll
  for (int p = 0; p < 3; p++) {
    bg0[p] = Wp[p] + (long)(n0 + w * 16 + ar) * 1024 + ak;
    bg1[p] = bg0[p] + 64L * 1024;
  }

  floatx4 acc[3][4][4];
#pragma unroll
  for (int p = 0; p < 3; p++)
#pragma unroll
    for (int r = 0; r < 4; r++)
#pragma unroll
      for (int c = 0; c < 4; c++)
        acc[p][r][c] = (floatx4){0.f, 0.f, 0.f, 0.f};

  {
    bf16_t* la = As + w * 512;
    async_copy16(ag0, la);
    async_copy16(ag1, la + 2048);
#pragma unroll
    for (int p = 0; p < 3; p++) {
      bf16_t* lb = Bsh[p] + w * 512;
      async_copy16(bg0[p], lb);
      async_copy16(bg1[p], lb + 2048);
    }
  }
  for (int i = 0; i < 32; i++) {
    __syncthreads();
    if (i + 1 < 32) {
      const int buf = (i + 1) & 1, k0 = (i + 1) * 32;
      bf16_t* la = As + buf * 4096 + w * 512;
      async_copy16(ag0 + k0, la);
      async_copy16(ag1 + k0, la + 2048);
#pragma unroll
      for (int p = 0; p < 3; p++) {
        bf16_t* lb = Bsh[p] + buf * 4096 + w * 512;
        async_copy16(bg0[p] + k0, lb);
        async_copy16(bg1[p] + k0, lb + 2048);
      }
    }
    const bf16_t* Ar = As + (i & 1) * 4096;
    bf16x8 afr[4];
#pragma unroll
    for (int r = 0; r < 4; r++)
      afr[r] = *(const bf16x8*)&Ar[(wr * 64 + r * 16 + lm) * 32 + (quad ^ swz) * 8];
#pragma unroll
    for (int p = 0; p < 3; p++) {
      const bf16_t* Br = Bsh[p] + (i & 1) * 4096;
      bf16x8 bfr[4];
#pragma unroll
      for (int c = 0; c < 4; c++)
        bfr[c] = *(const bf16x8*)&Br[(wc * 64 + c * 16 + lm) * 32 + (quad ^ swz) * 8];
#pragma unroll
      for (int r = 0; r < 4; r++)
#pragma unroll
        for (int c = 0; c < 4; c++)
          acc[p][r][c] = __builtin_amdgcn_mfma_f32_16x16x32_bf16(afr[r], bfr[c], acc[p][r][c], 0, 0, 0);
    }
  }

  const int rowBase = m0 + wr * 64, colBase = n0 + wc * 64;
  {
    bf16_t* C = qout + (long)batch * (2048L * 1024);
#pragma unroll
    for (int r = 0; r < 4; r++) {
      const int row = rowBase + r * 16 + quad * 4;
#pragma unroll
      for (int c = 0; c < 4; c++) {
        const int col = colBase + c * 16 + lm;
        const float bv_ = bq[col];
#pragma unroll
        for (int i = 0; i < 4; i++)
          C[(long)(row + i) * 1024 + col] = (bf16_t)(acc[0][r][c][i] + bv_);
      }
    }
  }
#pragma unroll
  for (int p = 1; p < 3; p++) {
    bf16_t* C = ((p == 1) ? kT : vT) + (long)batch * (1024L * 2048);
    const float* bias = (p == 1) ? bk : bv;
#pragma unroll
    for (int r = 0; r < 4; r++) {
      const int row = rowBase + r * 16 + quad * 4;
#pragma unroll
      for (int c = 0; c < 4; c++) {
        const int col = colBase + c * 16 + lm;
        const float bv_ = bias[col];
        bf16x4 pk;
#pragma unroll
        for (int i = 0; i < 4; i++) pk[i] = (bf16_t)(acc[p][r][c][i] + bv_);
        *(bf16x4*)(C + (long)col * 2048 + row) = pk;
      }
    }
  }
}

// ---------- generic NT GEMM with XCD swizzle ----------
template<int OUT_MODE, bool HAS_BIAS, int KSPLIT, int TOTAL, int BPZ, int GNX>
__global__ __launch_bounds__(256) void gemm_nt(
    const bf16_t* __restrict__ A, const bf16_t* __restrict__ B,
    void* __restrict__ C, void* __restrict__ C2, const float* __restrict__ bias,
    int lda, int ldb, int nk, long sA, long sB, long sC, int ldc, float alpha) {
  __shared__ bf16_t As[8192], Bs[8192];
  const int L = blockIdx.x + gridDim.x * (blockIdx.y + gridDim.y * blockIdx.z);
  const int V = (L & 7) * (TOTAL / 8) + (L >> 3);
  const int zp = V / BPZ;
  const int r_ = V % BPZ;
  const int n0 = (r_ % GNX) * 128;
  const int m0 = (r_ / GNX) * 128;
  const int nz = TOTAL / BPZ;
  const int nb = nz / KSPLIT;
  const int batch = zp % nb;
  const int kch   = zp / nb;
  const bf16_t* Ab = A + (long)batch * sA + (long)kch * (nk * 32);
  const bf16_t* Bb = B + (long)batch * sB + (long)kch * (nk * 32);

  floatx4 acc[4][4];
#pragma unroll
  for (int r = 0; r < 4; r++)
#pragma unroll
    for (int c = 0; c < 4; c++) acc[r][c] = (floatx4){0.f, 0.f, 0.f, 0.f};

  gemm_core(Ab, Bb, lda, ldb, nk, As, Bs, m0, n0, acc);

  const int lane = threadIdx.x & 63, w = threadIdx.x >> 6;
  const int wr = w >> 1, wc = w & 1, quad = lane >> 4, lm = lane & 15;
  const int rowBase = m0 + wr * 64, colBase = n0 + wc * 64;

  if (OUT_MODE == 0) {
    bf16_t* Cb = (bf16_t*)C + (long)batch * sC;
#pragma unroll
    for (int r = 0; r < 4; r++) {
      const int row = rowBase + r * 16 + quad * 4;
#pragma unroll
      for (int c = 0; c < 4; c++) {
        const int col = colBase + c * 16 + lm;
        const float bv_ = HAS_BIAS ? bias[col] : 0.f;
#pragma unroll
        for (int i = 0; i < 4; i++)
          Cb[(long)(row + i) * ldc + col] = (bf16_t)(acc[r][c][i] * alpha + bv_);
      }
    }
  } else if (OUT_MODE == 2) {
    float* Cf = (float*)C + (long)batch * sC;
#pragma unroll
    for (int r = 0; r < 4; r++) {
      const int row = rowBase + r * 16 + quad * 4;
#pragma unroll
      for (int c = 0; c < 4; c++) {
        const int col = colBase + c * 16 + lm;
        const float bv_ = HAS_BIAS ? bias[col] : 0.f;
#pragma unroll
        for (int i = 0; i < 4; i++)
          Cf[(long)(row + i) * ldc + col] = acc[r][c][i] * alpha + bv_;
      }
    }
  } else {
    float* Cf = (float*)(kch == 0 ? C : C2) + (long)batch * sC;
#pragma unroll
    for (int r = 0; r < 4; r++) {
      const int row = rowBase + r * 16 + quad * 4;
#pragma unroll
      for (int c = 0; c < 4; c++) {
        const int col = colBase + c * 16 + lm;
#pragma unroll
        for (int i = 0; i < 4; i++)
          Cf[(long)(row + i) * ldc + col] = acc[r][c][i] * alpha;
      }
    }
  }
}

extern "C" void kernel_launch(void* const* d_in, const int* in_sizes, int n_in,
                              void* d_out, int out_size, void* d_ws, size_t ws_size,
                              hipStream_t stream) {
  const float* x  = (const float*)d_in[0];
  const float* Wq = (const float*)d_in[1];
  const float* bq = (const float*)d_in[2];
  const float* Wk = (const float*)d_in[3];
  const float* bk = (const float*)d_in[4];
  const float* Wv = (const float*)d_in[5];
  const float* bv = (const float*)d_in[6];
  const float* Wo = (const float*)d_in[7];
  const float* bo = (const float*)d_in[8];
  float* out = (float*)d_out;

  const long NX = 8192L * 1024;
  const long NW = 1024L * 1024;
  const long NM = 4L * 1024 * 1024;

  bf16_t* ws  = (bf16_t*)d_ws;
  bf16_t* xb  = ws;
  bf16_t* Wqb = xb + NX;
  bf16_t* Wkb = Wqb + NW;
  bf16_t* Wvb = Wkb + NW;
  bf16_t* Wob = Wvb + NW;
  bf16_t* qb  = Wob + NW;
  bf16_t* kT  = qb + NX;
  bf16_t* vT  = kT + NX;
  float*  Mtf0 = (float*)xb;
  float*  Mtf1 = (float*)(vT + NX);
  bf16_t* MtTb = vT;
  bf16_t* Gb   = kT;

  CvtArgs ca;
  ca.seg[0] = {x,  xb,  NX};
  ca.seg[1] = {Wq, Wqb, NW};
  ca.seg[2] = {Wk, Wkb, NW};
  ca.seg[3] = {Wv, Wvb, NW};
  ca.seg[4] = {Wo, Wob, NW};
  cvt_multi<<<dim3(NX / 1024, 5), 256, 0, stream>>>(ca);

  qkv3<<<dim3(8, 16, 4), 256, 0, stream>>>(xb, Wqb, Wkb, Wvb, bq, bk, bv, qb, kT, vT);

  gemm_nt<3, false, 2, 512, 64, 8><<<dim3(8, 8, 8), 256, 0, stream>>>(
      kT, vT, Mtf0, Mtf1, nullptr, 2048, 2048, 32,
      1024L * 2048, 1024L * 2048, 1024L * 1024, 1024, 0.125f);

  reduce2_cvt<<<NM / 1024, 256, 0, stream>>>(Mtf0, Mtf1, MtTb, NM);

  gemm_nt<0, false, 1, 256, 64, 8><<<dim3(8, 8, 4), 256, 0, stream>>>(
      Wob, MtTb, Gb, nullptr, nullptr, 1024, 1024, 32,
      0L, 1024L * 1024, 1024L * 1024, 1024, 1.0f);

  gemm_nt<2, true, 1, 512, 128, 8><<<dim3(8, 16, 4), 256, 0, stream>>>(
      qb, Gb, out, nullptr, bo, 1024, 1024, 32,
      2048L * 1024, 1024L * 1024, 2048L * 1024, 1024, 1.0f);
}